// Round 7
// baseline (476.824 us; speedup 1.0000x reference)
//
#include <hip/hip_runtime.h>
#include <hip/hip_bf16.h>

#define B 32
#define C_IN 192
#define T 8192
#define H 192
#define N_PH 1024
#define OUT 4
#define ROW_MAX 7168          // max total frames = 7 * 1024
#define PROWS (N_PH + 2)      // padded rows: t = -1 .. N_PH
#define ROWP (2 * H)          // row pitch: hi plane [0,H), lo plane [H,2H)

typedef __attribute__((ext_vector_type(8))) short short8;
typedef __attribute__((ext_vector_type(4))) float f32x4;
typedef unsigned short ushort_t;

__device__ inline ushort_t f2bf(float f) {
    unsigned u = __builtin_bit_cast(unsigned, f);
    unsigned r = u + 0x7fffu + ((u >> 16) & 1u);   // RNE
    return (ushort_t)(r >> 16);
}
__device__ inline float bf2f(ushort_t h) {
    unsigned u = ((unsigned)h) << 16;
    return __builtin_bit_cast(float, u);
}
// split x into hi+lo bf16 pair (~17-bit effective mantissa) -- accuracy-mandatory
__device__ inline void split_bf(float x, ushort_t& hi, ushort_t& lo) {
    hi = f2bf(x);
    lo = f2bf(x - bf2f(hi));
}

// ---- fused segment-mean: scan + pool + split-bf16 time-major output ----------
// block = (b, 32-phoneme tile). Stages the tile's frame window per 32-channel
// group, pools, writes specT[b][j][hi:H|lo:H] directly (no fp32 round-trip).
__global__ __launch_bounds__(256) void segmeanT_kernel(const float* __restrict__ x,
                                                       const int* __restrict__ wdur,
                                                       ushort_t* __restrict__ specT) {
    int b   = blockIdx.y;
    int jt0 = blockIdx.x * 32;
    __shared__ int e_s[N_PH];
    __shared__ int part[256];
    __shared__ __align__(16) float tile[32][225];        // 28.8 KB
    __shared__ __align__(16) ushort_t resh[32][32], resl[32][32];
    int tid = threadIdx.x;
    // inclusive scan of w[b][:] (1024 ints, 4/thread)
    int4 w4 = ((const int4*)(wdur + b * N_PH))[tid];
    int c0s = w4.x, c1s = c0s + w4.y, c2s = c1s + w4.z, c3s = c2s + w4.w;
    part[tid] = c3s;
    __syncthreads();
    for (int off = 1; off < 256; off <<= 1) {
        int v = (tid >= off) ? part[tid - off] : 0;
        __syncthreads();
        part[tid] += v;
        __syncthreads();
    }
    int pre = tid ? part[tid - 1] : 0;
    e_s[4 * tid + 0] = pre + c0s;
    e_s[4 * tid + 1] = pre + c1s;
    e_s[4 * tid + 2] = pre + c2s;
    e_s[4 * tid + 3] = pre + c3s;
    __syncthreads();
    int s_base = jt0 ? e_s[jt0 - 1] : 0;
    int nf = e_s[jt0 + 31] - s_base;        // <= 32*7 = 224
    int wv = tid >> 6, lane = tid & 63;
    int j_loc = tid & 31;
    int j = jt0 + j_loc;
    int s0 = j ? e_s[j - 1] : 0;
    int e0 = e_s[j];
    int fs = s0 - s_base, fe = e0 - s_base;
    float inv = (e0 > s0) ? 1.f / (float)(e0 - s0) : 0.f;
    int cb = (tid >> 5) * 4;                // 8 groups x 4 channels = 32
    for (int hh = 0; hh < 6; ++hh) {
        int c0 = hh * 32;
        // stage: 32 channels x nf frames, coalesced runs
        for (int cl = wv; cl < 32; cl += 4) {
            const float* xr = x + ((size_t)b * C_IN + c0 + cl) * T + s_base;
            for (int f = lane; f < nf; f += 64) tile[cl][f] = xr[f];
        }
        __syncthreads();
        // pool: thread -> (j_loc, 4 channels)
        for (int cc = 0; cc < 4; ++cc) {
            int cl = cb + cc;
            float sum = 0.f;
            for (int f = fs; f < fe; ++f) sum += tile[cl][f];
            ushort_t hi, lo;
            split_bf(sum * inv, hi, lo);
            resh[j_loc][cl] = hi;
            resl[j_loc][cl] = lo;
        }
        __syncthreads();
        // write: 32 rows x (4 hi + 4 lo) short8 chunks = 256, one per thread
        {
            int row = tid >> 3, k = tid & 7;
            int plane = k >> 2, ch = (k & 3) * 8;
            ushort_t* dst = specT + ((size_t)b * N_PH + jt0 + row) * ROWP
                          + plane * H + c0 + ch;
            const ushort_t* src = plane ? &resl[row][ch] : &resh[row][ch];
            *(short8*)dst = *(short8*)src;
        }
        __syncthreads();
    }
}

// ---------------- weight prep: MFMA-fragment-ordered, split hi/lo (R4-proven) -----
// Fragment slot (kt, s, nt): 512 ushort = lane*8 + j.
// Stored value: w[o = nt*16 + (lane&15)][k_in_tap = s*32 + (lane>>4)*8 + j][tap kt]
__device__ inline void wfrag_one(const float* __restrict__ w, ushort_t* __restrict__ wtf,
                                 int taps, int idx, int ntot) {
    int j  = idx & 7;
    int l  = (idx >> 3) & 63;
    int slot = idx >> 9;             // (kt*6 + s)*12 + nt
    int nt = slot % 12;
    int ss = (slot / 12) % 6;
    int kt = slot / 72;
    int o  = nt * 16 + (l & 15);
    int i  = ss * 32 + ((l >> 4) << 3) + j;
    float v = (taps == 1) ? w[o * C_IN + i] : w[(o * H + i) * 3 + kt];
    ushort_t hi, lo;
    split_bf(v, hi, lo);
    wtf[idx] = hi;
    wtf[idx + ntot] = lo;
}
__global__ void wfrag_all_kernel(const float* __restrict__ pw, const float* __restrict__ w0,
                                 const float* __restrict__ w1,
                                 ushort_t* __restrict__ wpre, ushort_t* __restrict__ w0t,
                                 ushort_t* __restrict__ w1t) {
    int idx = blockIdx.x * 256 + threadIdx.x;
    const int n1 = 36864, n3 = 110592;
    if (idx < n1) { wfrag_one(pw, wpre, 1, idx, n1); return; }
    idx -= n1;
    if (idx < n3) { wfrag_one(w0, w0t, 3, idx, n3); return; }
    idx -= n3;
    if (idx < n3) wfrag_one(w1, w1t, 3, idx, n3);
}

// ---------------- fused MFMA GEMM: conv(taps)+bias [+relu+LN] +mask [+final proj] ----
// 32-row tiles (grid 1024 -> 4 blocks/CU), A-only register prefetch (B is
// L1-resident). Wave = 1 m-frag (mhalf*16) x 6 n-tiles (nhalf*6..+5); acc 24 VGPR.
__global__ __launch_bounds__(256) void gemm_fused_kernel(
    const ushort_t* __restrict__ in, int in_rows,
    const ushort_t* __restrict__ wt,
    const float* __restrict__ bias,
    const float* __restrict__ mask,
    const float* __restrict__ g, const float* __restrict__ beta,
    ushort_t* __restrict__ out,
    const float* __restrict__ lw, const float* __restrict__ lb,
    float* __restrict__ fout,
    int taps, int do_ln, int nmask, int fin)
{
    int b  = blockIdx.y;
    int t0 = blockIdx.x * 32;
    int tid = threadIdx.x;
    int lane = tid & 63;
    int wv = tid >> 6;
    int mhalf = wv & 1;                 // m-frag at mhalf*16
    int nhalf = wv >> 1;                // n-tiles nhalf*6 .. +5

    __shared__ float ep[32][193];       // 24.7 KB
    __shared__ float g_s[H], b_s[H], m_s[32], mstat[32], rstat[32];
    if (tid < H) { g_s[tid] = do_ln ? g[tid] : 1.f; b_s[tid] = do_ln ? beta[tid] : 0.f; }
    if (tid < 32) m_s[tid] = mask[b * N_PH + t0 + tid];

    // zero halo rows (t=-1 and t=N_PH), both planes (skip in fin mode: no store)
    short8 z8 = {0, 0, 0, 0, 0, 0, 0, 0};
    if (!fin) {
        if (t0 == 0 && tid < ROWP / 8)
            *(short8*)(out + (size_t)b * PROWS * ROWP + tid * 8) = z8;
        if (t0 == N_PH - 32 && tid < ROWP / 8)
            *(short8*)(out + ((size_t)b * PROWS + N_PH + 1) * ROWP + tid * 8) = z8;
    }

    int m  = lane & 15;                 // A time-row / B channel / D col
    int kg = (lane >> 4) << 3;          // k offset within 32-step: 0,8,16,24
    int ntotw = taps * 36864;           // hi-plane size; lo at +ntotw
    int pad = taps >> 1;

    const ushort_t* inb = in + (size_t)b * in_rows * ROWP;
    int trow = t0 + mhalf * 16 + m;

    f32x4 acc[6];
#pragma unroll
    for (int ntl = 0; ntl < 6; ++ntl) {
        float bb = bias[(nhalf * 6 + ntl) * 16 + m];
        acc[ntl] = (f32x4){bb, bb, bb, bb};
    }

    int iters = taps * 6;               // 6 or 18 (even)
    // A double-buffered prefetch; B loaded in-loop (L1-hot, 24 KB/iter/block)
    short8 pah, pal, qah, qal;
    {
        const ushort_t* ar = inb + (long)(trow - pad) * ROWP + kg;   // it=0: kt=0,s=0
        pah = *(const short8*)(ar);
        pal = *(const short8*)(ar + H);
    }
#pragma unroll 1
    for (int it = 0; it < iters; it += 2) {
        {   // prefetch A for it+1
            int i1 = it + 1, kt = i1 / 6, s = i1 - kt * 6;
            const ushort_t* ar = inb + (long)(trow + kt - pad) * ROWP + s * 32 + kg;
            qah = *(const short8*)(ar);
            qal = *(const short8*)(ar + H);
        }
        {   // B + MFMA for it
            const ushort_t* wb = wt + ((size_t)(it * 12 + nhalf * 6) << 9) + (lane << 3);
#pragma unroll
            for (int n = 0; n < 6; ++n) {
                short8 bh = *(const short8*)(wb + (n << 9));
                short8 bl = *(const short8*)(wb + (n << 9) + ntotw);
                acc[n] = __builtin_amdgcn_mfma_f32_16x16x32_bf16(pah, bh, acc[n], 0, 0, 0);
                acc[n] = __builtin_amdgcn_mfma_f32_16x16x32_bf16(pal, bh, acc[n], 0, 0, 0);
                acc[n] = __builtin_amdgcn_mfma_f32_16x16x32_bf16(pah, bl, acc[n], 0, 0, 0);
            }
        }
        if (it + 2 < iters) {   // prefetch A for it+2
            int i2 = it + 2, kt = i2 / 6, s = i2 - kt * 6;
            const ushort_t* ar = inb + (long)(trow + kt - pad) * ROWP + s * 32 + kg;
            pah = *(const short8*)(ar);
            pal = *(const short8*)(ar + H);
        }
        {   // B + MFMA for it+1
            const ushort_t* wb = wt + ((size_t)((it + 1) * 12 + nhalf * 6) << 9) + (lane << 3);
#pragma unroll
            for (int n = 0; n < 6; ++n) {
                short8 bh = *(const short8*)(wb + (n << 9));
                short8 bl = *(const short8*)(wb + (n << 9) + ntotw);
                acc[n] = __builtin_amdgcn_mfma_f32_16x16x32_bf16(qah, bh, acc[n], 0, 0, 0);
                acc[n] = __builtin_amdgcn_mfma_f32_16x16x32_bf16(qal, bh, acc[n], 0, 0, 0);
                acc[n] = __builtin_amdgcn_mfma_f32_16x16x32_bf16(qah, bl, acc[n], 0, 0, 0);
            }
        }
    }

    __syncthreads();   // covers g_s/b_s/m_s staging

    // write pre-LN (or final-masked) values to LDS, C/D layout -> [time][channel]
    int rbase = (lane >> 4) << 2;
#pragma unroll
    for (int ntl = 0; ntl < 6; ++ntl) {
        int o = (nhalf * 6 + ntl) * 16 + m;
#pragma unroll
        for (int r = 0; r < 4; ++r) {
            int t_loc = mhalf * 16 + rbase + r;
            float mm = m_s[t_loc];
            float v = acc[ntl][r];
            if (do_ln) {
                v = fmaxf(v * mm, 0.f) * mm;     // relu(conv*mask)*mask -> LN input
            } else {
                for (int q = 0; q < nmask; ++q) v *= mm;
            }
            ep[t_loc][o] = v;
        }
    }
    __syncthreads();

    // LN stats: one thread per time row (scalar reads -- ep pitch 193 not 16B aligned)
    if (do_ln && tid < 32) {
        float s = 0.f, ss = 0.f;
        for (int c = 0; c < H; ++c) {
            float v = ep[tid][c];
            s += v;
            ss += v * v;
        }
        float mean = s * (1.f / (float)H);
        mstat[tid] = mean;
        rstat[tid] = rsqrtf(ss * (1.f / (float)H) - mean * mean + 1e-5f);
    }
    __syncthreads();

    int row = tid >> 3;                 // 32 rows, 8 threads/row
    int q = tid & 7;                    // 24 channels each
    if (fin) {
        // fused final projection: p[o] = (sum_c lw[o][c] * (ln(c)*mk) + lb[o]) * mk
        float mean = mstat[row], rstd = rstat[row], mk = m_s[row];
        float a0 = 0.f, a1 = 0.f, a2 = 0.f, a3 = 0.f;
#pragma unroll 1
        for (int c = q * 24; c < q * 24 + 24; ++c) {
            float y = ((ep[row][c] - mean) * rstd * g_s[c] + b_s[c]) * mk;
            a0 += lw[0 * H + c] * y;
            a1 += lw[1 * H + c] * y;
            a2 += lw[2 * H + c] * y;
            a3 += lw[3 * H + c] * y;
        }
        a0 += __shfl_xor(a0, 1); a0 += __shfl_xor(a0, 2); a0 += __shfl_xor(a0, 4);
        a1 += __shfl_xor(a1, 1); a1 += __shfl_xor(a1, 2); a1 += __shfl_xor(a1, 4);
        a2 += __shfl_xor(a2, 1); a2 += __shfl_xor(a2, 2); a2 += __shfl_xor(a2, 4);
        a3 += __shfl_xor(a3, 1); a3 += __shfl_xor(a3, 2); a3 += __shfl_xor(a3, 4);
        if (q == 0) {
            int t = t0 + row;
            float* ob = fout + (size_t)b * OUT * N_PH + t;
            ob[0 * N_PH] = (a0 + lb[0]) * mk;
            ob[1 * N_PH] = (a1 + lb[1]) * mk;
            ob[2 * N_PH] = (a2 + lb[2]) * mk;
            ob[3 * N_PH] = (a3 + lb[3]) * mk;
        }
        return;
    }

    // store: 8 threads per row, 24 channels each, split bf16
    float mean = 0.f, rstd = 1.f, mfac = 1.f;
    if (do_ln) {
        mean = mstat[row];
        rstd = rstat[row];
        float mk = m_s[row];
        mfac = (nmask == 2) ? mk * mk : mk;
    }
    ushort_t* orow = out + ((size_t)b * PROWS + t0 + row + 1) * ROWP + q * 24;
#pragma unroll
    for (int i0 = 0; i0 < 24; i0 += 8) {
        ushort_t th[8], tl[8];
#pragma unroll
        for (int k2 = 0; k2 < 8; ++k2) {
            int c = q * 24 + i0 + k2;
            float v = ep[row][c];
            float y = do_ln ? ((v - mean) * rstd * g_s[c] + b_s[c]) * mfac : v;
            split_bf(y, th[k2], tl[k2]);
        }
        *(short8*)(orow + i0) = *(short8*)th;
        *(short8*)(orow + H + i0) = *(short8*)tl;
    }
}

extern "C" void kernel_launch(void* const* d_in, const int* in_sizes, int n_in,
                              void* d_out, int out_size, void* d_ws, size_t ws_size,
                              hipStream_t stream) {
    const float* x      = (const float*)d_in[0];
    const float* x_mask = (const float*)d_in[1];
    const int*   w      = (const int*)d_in[2];
    const float* pre_w  = (const float*)d_in[3];
    const float* pre_b  = (const float*)d_in[4];
    const float* conv0_w = (const float*)d_in[5];
    const float* conv0_b = (const float*)d_in[6];
    const float* ln0_g   = (const float*)d_in[7];
    const float* ln0_b   = (const float*)d_in[8];
    const float* conv1_w = (const float*)d_in[9];
    const float* conv1_b = (const float*)d_in[10];
    const float* ln1_g   = (const float*)d_in[11];
    const float* ln1_b   = (const float*)d_in[12];
    const float* lin_w   = (const float*)d_in[13];
    const float* lin_b   = (const float*)d_in[14];
    float* out = (float*)d_out;

    // workspace layout
    char* ws = (char*)d_ws;
    size_t off = 0;
    ushort_t* bufA = (ushort_t*)(ws + off); off += (size_t)B * PROWS * ROWP * sizeof(ushort_t);
    ushort_t* bufB = (ushort_t*)(ws + off); off += (size_t)B * PROWS * ROWP * sizeof(ushort_t);
    ushort_t* wpre = (ushort_t*)(ws + off); off += (size_t)2 * 36864 * sizeof(ushort_t);
    ushort_t* w0t  = (ushort_t*)(ws + off); off += (size_t)2 * 110592 * sizeof(ushort_t);
    ushort_t* w1t  = (ushort_t*)(ws + off); off += (size_t)2 * 110592 * sizeof(ushort_t);
    // specT aliases bufB: consumed by pregemm before conv0 first writes bufB
    ushort_t* specT = bufB;

    // all weight fragments in one dispatch
    wfrag_all_kernel<<<(36864 + 2 * 110592 + 255) / 256, 256, 0, stream>>>(
        pre_w, conv0_w, conv1_w, wpre, w0t, w1t);

    // fused scan + segment-mean + split-bf16 time-major output
    dim3 gs(N_PH / 32, B);
    segmeanT_kernel<<<gs, 256, 0, stream>>>(x, w, specT);

    dim3 gg(N_PH / 32, B);
    // pre linear: specT (pitch N_PH rows) -> bufA (mask applied for conv0 input)
    gemm_fused_kernel<<<gg, 256, 0, stream>>>(specT, N_PH, wpre, pre_b, x_mask,
                                              ln0_g, ln0_b, bufA,
                                              nullptr, nullptr, nullptr, 1, 0, 1, 0);
    // block 0: bufA -> bufB  (out = ln0*mask, + conv1's leading mask)
    gemm_fused_kernel<<<gg, 256, 0, stream>>>(bufA + ROWP, PROWS, w0t, conv0_b, x_mask,
                                              ln0_g, ln0_b, bufB,
                                              nullptr, nullptr, nullptr, 3, 1, 2, 0);
    // block 1 + fused final projection: bufB -> out
    gemm_fused_kernel<<<gg, 256, 0, stream>>>(bufB + ROWP, PROWS, w1t, conv1_b, x_mask,
                                              ln1_g, ln1_b, bufA,
                                              lin_w, lin_b, out, 3, 1, 1, 1);
}

// Round 8
// 426.244 us; speedup vs baseline: 1.1187x; 1.1187x over previous
//
#include <hip/hip_runtime.h>
#include <hip/hip_bf16.h>

#define B 32
#define C_IN 192
#define T 8192
#define H 192
#define N_PH 1024
#define OUT 4
#define ROW_MAX 7168          // max total frames = 7 * 1024
#define PROWS (N_PH + 2)      // padded rows: t = -1 .. N_PH
#define ROWP (2 * H)          // row pitch: hi plane [0,H), lo plane [H,2H)

typedef __attribute__((ext_vector_type(8))) short short8;
typedef __attribute__((ext_vector_type(4))) float f32x4;
typedef unsigned short ushort_t;

__device__ inline ushort_t f2bf(float f) {
    unsigned u = __builtin_bit_cast(unsigned, f);
    unsigned r = u + 0x7fffu + ((u >> 16) & 1u);   // RNE
    return (ushort_t)(r >> 16);
}
__device__ inline float bf2f(ushort_t h) {
    unsigned u = ((unsigned)h) << 16;
    return __builtin_bit_cast(float, u);
}
// split x into hi+lo bf16 pair (~17-bit effective mantissa) -- accuracy-mandatory
__device__ inline void split_bf(float x, ushort_t& hi, ushort_t& lo) {
    hi = f2bf(x);
    lo = f2bf(x - bf2f(hi));
}

// ---------------- K2: segment mean with inline duration scan (R5-proven) ----------
__global__ __launch_bounds__(256) void segmean_kernel(const float* __restrict__ x,
                                                      const int* __restrict__ wdur,
                                                      float* __restrict__ spec) {
    int bc = blockIdx.x;
    int b = bc / C_IN;
    int c = bc % C_IN;
    __shared__ int e_s[N_PH];
    __shared__ int part[256];
    __shared__ float row[ROW_MAX];
    int tid = threadIdx.x;
    // inline inclusive scan of w[b][:] (1024 ints, 4/thread)
    int4 w4 = ((const int4*)(wdur + b * N_PH))[tid];
    int c0 = w4.x, c1 = c0 + w4.y, c2 = c1 + w4.z, c3 = c2 + w4.w;
    part[tid] = c3;
    __syncthreads();
    for (int off = 1; off < 256; off <<= 1) {
        int v = (tid >= off) ? part[tid - off] : 0;
        __syncthreads();
        part[tid] += v;
        __syncthreads();
    }
    int pre = tid ? part[tid - 1] : 0;
    e_s[4 * tid + 0] = pre + c0;
    e_s[4 * tid + 1] = pre + c1;
    e_s[4 * tid + 2] = pre + c2;
    e_s[4 * tid + 3] = pre + c3;
    __syncthreads();
    int emax = e_s[N_PH - 1];           // <= ROW_MAX by construction (w < 8)
    const float4* xr4 = (const float4*)(x + ((size_t)b * C_IN + c) * T);
    float4* row4 = (float4*)row;
    int nv = (emax + 3) >> 2;
    for (int t = tid; t < nv; t += 256) row4[t] = xr4[t];
    __syncthreads();
    float* sp = spec + ((size_t)b * C_IN + c) * N_PH;
    for (int j = tid; j < N_PH; j += 256) {
        int s0 = j ? e_s[j - 1] : 0;
        int e0 = e_s[j];
        float sum = 0.f;
        for (int t = s0; t < e0; ++t) sum += row[t];
        sp[j] = (e0 > s0) ? sum / (float)(e0 - s0) : 0.f;
    }
}

// ---------------- transpose spec -> time-major split bf16 [b][j][hi:H|lo:H] -------
__global__ __launch_bounds__(256) void transpose_spec_kernel(const float* __restrict__ spec,
                                                             ushort_t* __restrict__ specT) {
    int jt = blockIdx.x * 32;
    int ct = (blockIdx.y % (C_IN / 32)) * 32;
    int b  = blockIdx.y / (C_IN / 32);
    __shared__ float tile[32][33];
    int tx = threadIdx.x & 31;
    int ty = threadIdx.x >> 5;     // 8 rows per pass
    const float* sb = spec + ((size_t)b * C_IN + ct) * N_PH + jt;
    for (int r = ty; r < 32; r += 8) tile[r][tx] = sb[(size_t)r * N_PH + tx]; // [c_loc][j_loc]
    __syncthreads();
    ushort_t* ob = specT + ((size_t)b * N_PH + jt) * ROWP + ct;
    for (int r = ty; r < 32; r += 8) {
        ushort_t hi, lo;
        split_bf(tile[tx][r], hi, lo);
        ob[(size_t)r * ROWP + tx] = hi;
        ob[(size_t)r * ROWP + H + tx] = lo;
    }
}

// ---------------- weight prep: MFMA-fragment-ordered, split hi/lo (R4-proven) -----
// Fragment slot (kt, s, nt): 512 ushort = lane*8 + j.
// Stored value: w[o = nt*16 + (lane&15)][k_in_tap = s*32 + (lane>>4)*8 + j][tap kt]
__device__ inline void wfrag_one(const float* __restrict__ w, ushort_t* __restrict__ wtf,
                                 int taps, int idx, int ntot) {
    int j  = idx & 7;
    int l  = (idx >> 3) & 63;
    int slot = idx >> 9;             // (kt*6 + s)*12 + nt
    int nt = slot % 12;
    int ss = (slot / 12) % 6;
    int kt = slot / 72;
    int o  = nt * 16 + (l & 15);
    int i  = ss * 32 + ((l >> 4) << 3) + j;
    float v = (taps == 1) ? w[o * C_IN + i] : w[(o * H + i) * 3 + kt];
    ushort_t hi, lo;
    split_bf(v, hi, lo);
    wtf[idx] = hi;
    wtf[idx + ntot] = lo;
}
__global__ void wfrag_all_kernel(const float* __restrict__ pw, const float* __restrict__ w0,
                                 const float* __restrict__ w1,
                                 ushort_t* __restrict__ wpre, ushort_t* __restrict__ w0t,
                                 ushort_t* __restrict__ w1t) {
    int idx = blockIdx.x * 256 + threadIdx.x;
    const int n1 = 36864, n3 = 110592;
    if (idx < n1) { wfrag_one(pw, wpre, 1, idx, n1); return; }
    idx -= n1;
    if (idx < n3) { wfrag_one(w0, w0t, 3, idx, n3); return; }
    idx -= n3;
    if (idx < n3) wfrag_one(w1, w1t, 3, idx, n3);
}

// ---------------- fused MFMA GEMM: conv(taps)+bias [+relu+LN] +mask [+final proj] ----
// 64-row tiles (grid 512). Wave split: wv = n-quarter; each wave computes ALL
// 4 m-frags (64 rows) x 3 n-tiles -> per-iter loads: A 8, B 6 (halved vs R5's 12)
// at the same 36 MFMAs/wave/iter. A-only register double-buffer prefetch; B is
// L1-hot (24 KB working set). acc = 12 f32x4 = 48 VGPR.
__global__ __launch_bounds__(256) void gemm_fused_kernel(
    const ushort_t* __restrict__ in, int in_rows,
    const ushort_t* __restrict__ wt,
    const float* __restrict__ bias,
    const float* __restrict__ mask,
    const float* __restrict__ g, const float* __restrict__ beta,
    ushort_t* __restrict__ out,
    const float* __restrict__ lw, const float* __restrict__ lb,
    float* __restrict__ fout,
    int taps, int do_ln, int nmask, int fin)
{
    int b  = blockIdx.y;
    int t0 = blockIdx.x * 64;
    int tid = threadIdx.x;
    int lane = tid & 63;
    int wv = tid >> 6;                  // n-quarter: n-tiles wv*3 .. wv*3+2

    __shared__ float ep[64][193];
    __shared__ float g_s[H], b_s[H], m_s[64], mstat[64], rstat[64];
    if (tid < H) { g_s[tid] = do_ln ? g[tid] : 1.f; b_s[tid] = do_ln ? beta[tid] : 0.f; }
    if (tid < 64) m_s[tid] = mask[b * N_PH + t0 + tid];

    // zero halo rows (t=-1 and t=N_PH), both planes (skip in fin mode: no store)
    short8 z8 = {0, 0, 0, 0, 0, 0, 0, 0};
    if (!fin) {
        if (t0 == 0 && tid < ROWP / 8)
            *(short8*)(out + (size_t)b * PROWS * ROWP + tid * 8) = z8;
        if (t0 == N_PH - 64 && tid < ROWP / 8)
            *(short8*)(out + ((size_t)b * PROWS + N_PH + 1) * ROWP + tid * 8) = z8;
    }

    int m  = lane & 15;                 // A time-row / B channel / D col
    int kg = (lane >> 4) << 3;          // k offset within 32-step: 0,8,16,24
    int ntotw = taps * 36864;           // hi-plane size; lo at +ntotw
    int pad = taps >> 1;

    const ushort_t* inb = in + (size_t)b * in_rows * ROWP;
    int trow = t0 + m;                  // + mf*16 per m-frag

    f32x4 acc[4][3];
#pragma unroll
    for (int ntl = 0; ntl < 3; ++ntl) {
        float bb = bias[(wv * 3 + ntl) * 16 + m];
#pragma unroll
        for (int mf = 0; mf < 4; ++mf) acc[mf][ntl] = (f32x4){bb, bb, bb, bb};
    }

    int iters = taps * 6;               // 6 or 18 (even)
    // A double-buffered prefetch (8 loads/iter); B loaded at use (L1-hot)
    short8 pa[4][2], qa[4][2];
#define LOADA(IT, BUF) do {                                                        \
        int kt_ = (IT) / 6, s_ = (IT) - kt_ * 6;                                   \
        _Pragma("unroll") for (int mf_ = 0; mf_ < 4; ++mf_) {                      \
            const ushort_t* ar_ = inb + (long)(trow + mf_ * 16 + kt_ - pad) * ROWP \
                                + s_ * 32 + kg;                                    \
            BUF[mf_][0] = *(const short8*)(ar_);                                   \
            BUF[mf_][1] = *(const short8*)(ar_ + H); }                             \
    } while (0)
#define MFMAGRP(IT, BUF) do {                                                      \
        const ushort_t* wb_ = wt + ((size_t)((IT) * 12 + wv * 3) << 9) + (lane << 3); \
        _Pragma("unroll") for (int ntl_ = 0; ntl_ < 3; ++ntl_) {                   \
            short8 bh_ = *(const short8*)(wb_ + (ntl_ << 9));                      \
            short8 bl_ = *(const short8*)(wb_ + (ntl_ << 9) + ntotw);              \
            _Pragma("unroll") for (int mf_ = 0; mf_ < 4; ++mf_) {                  \
                acc[mf_][ntl_] = __builtin_amdgcn_mfma_f32_16x16x32_bf16(          \
                    BUF[mf_][0], bh_, acc[mf_][ntl_], 0, 0, 0);                    \
                acc[mf_][ntl_] = __builtin_amdgcn_mfma_f32_16x16x32_bf16(          \
                    BUF[mf_][1], bh_, acc[mf_][ntl_], 0, 0, 0);                    \
                acc[mf_][ntl_] = __builtin_amdgcn_mfma_f32_16x16x32_bf16(          \
                    BUF[mf_][0], bl_, acc[mf_][ntl_], 0, 0, 0); } }                \
    } while (0)

    LOADA(0, pa);
#pragma unroll 1
    for (int it = 0; it < iters; it += 2) {
        LOADA(it + 1, qa);
        MFMAGRP(it, pa);
        if (it + 2 < iters) LOADA(it + 2, pa);
        MFMAGRP(it + 1, qa);
    }
#undef LOADA
#undef MFMAGRP

    __syncthreads();   // covers g_s/b_s/m_s staging

    // write pre-LN (or final-masked) values to LDS, C/D layout -> [time][channel]
    int rbase = (lane >> 4) << 2;
#pragma unroll
    for (int mf = 0; mf < 4; ++mf) {
#pragma unroll
        for (int ntl = 0; ntl < 3; ++ntl) {
            int o = (wv * 3 + ntl) * 16 + m;
#pragma unroll
            for (int r = 0; r < 4; ++r) {
                int t_loc = mf * 16 + rbase + r;
                float mm = m_s[t_loc];
                float v = acc[mf][ntl][r];
                if (do_ln) {
                    v = fmaxf(v * mm, 0.f) * mm;     // relu(conv*mask)*mask -> LN input
                } else {
                    for (int q = 0; q < nmask; ++q) v *= mm;
                }
                ep[t_loc][o] = v;
            }
        }
    }
    __syncthreads();

    // LN stats: one thread per time row (scalar reads -- ep pitch 193 not 16B aligned)
    if (do_ln && tid < 64) {
        float s = 0.f, ss = 0.f;
        for (int c = 0; c < H; ++c) {
            float v = ep[tid][c];
            s += v;
            ss += v * v;
        }
        float mean = s * (1.f / (float)H);
        mstat[tid] = mean;
        rstat[tid] = rsqrtf(ss * (1.f / (float)H) - mean * mean + 1e-5f);
    }
    __syncthreads();

    int row = tid >> 2;
    int q = tid & 3;
    if (fin) {
        // fused final projection: p[o] = (sum_c lw[o][c] * (ln(c)*mk) + lb[o]) * mk
        float mean = mstat[row], rstd = rstat[row], mk = m_s[row];
        float a0 = 0.f, a1 = 0.f, a2 = 0.f, a3 = 0.f;
#pragma unroll 1
        for (int c = q * 48; c < q * 48 + 48; ++c) {
            float y = ((ep[row][c] - mean) * rstd * g_s[c] + b_s[c]) * mk;
            a0 += lw[0 * H + c] * y;
            a1 += lw[1 * H + c] * y;
            a2 += lw[2 * H + c] * y;
            a3 += lw[3 * H + c] * y;
        }
        a0 += __shfl_xor(a0, 1); a0 += __shfl_xor(a0, 2);
        a1 += __shfl_xor(a1, 1); a1 += __shfl_xor(a1, 2);
        a2 += __shfl_xor(a2, 1); a2 += __shfl_xor(a2, 2);
        a3 += __shfl_xor(a3, 1); a3 += __shfl_xor(a3, 2);
        if (q == 0) {
            int t = t0 + row;
            float* ob = fout + (size_t)b * OUT * N_PH + t;
            ob[0 * N_PH] = (a0 + lb[0]) * mk;
            ob[1 * N_PH] = (a1 + lb[1]) * mk;
            ob[2 * N_PH] = (a2 + lb[2]) * mk;
            ob[3 * N_PH] = (a3 + lb[3]) * mk;
        }
        return;
    }

    // store: 4 threads per row, 48 channels each, split bf16
    float mean = 0.f, rstd = 1.f, mfac = 1.f;
    if (do_ln) {
        mean = mstat[row];
        rstd = rstat[row];
        float mk = m_s[row];
        mfac = (nmask == 2) ? mk * mk : mk;
    }
    ushort_t* orow = out + ((size_t)b * PROWS + t0 + row + 1) * ROWP + q * 48;
#pragma unroll
    for (int i0 = 0; i0 < 48; i0 += 8) {
        ushort_t th[8], tl[8];
#pragma unroll
        for (int k2 = 0; k2 < 8; ++k2) {
            int c = q * 48 + i0 + k2;
            float v = ep[row][c];
            float y = do_ln ? ((v - mean) * rstd * g_s[c] + b_s[c]) * mfac : v;
            split_bf(y, th[k2], tl[k2]);
        }
        *(short8*)(orow + i0) = *(short8*)th;
        *(short8*)(orow + H + i0) = *(short8*)tl;
    }
}

extern "C" void kernel_launch(void* const* d_in, const int* in_sizes, int n_in,
                              void* d_out, int out_size, void* d_ws, size_t ws_size,
                              hipStream_t stream) {
    const float* x      = (const float*)d_in[0];
    const float* x_mask = (const float*)d_in[1];
    const int*   w      = (const int*)d_in[2];
    const float* pre_w  = (const float*)d_in[3];
    const float* pre_b  = (const float*)d_in[4];
    const float* conv0_w = (const float*)d_in[5];
    const float* conv0_b = (const float*)d_in[6];
    const float* ln0_g   = (const float*)d_in[7];
    const float* ln0_b   = (const float*)d_in[8];
    const float* conv1_w = (const float*)d_in[9];
    const float* conv1_b = (const float*)d_in[10];
    const float* ln1_g   = (const float*)d_in[11];
    const float* ln1_b   = (const float*)d_in[12];
    const float* lin_w   = (const float*)d_in[13];
    const float* lin_b   = (const float*)d_in[14];
    float* out = (float*)d_out;

    // workspace layout
    char* ws = (char*)d_ws;
    size_t off = 0;
    float* spec = (float*)(ws + off);       off += (size_t)B * C_IN * N_PH * sizeof(float);
    ushort_t* bufA = (ushort_t*)(ws + off); off += (size_t)B * PROWS * ROWP * sizeof(ushort_t);
    ushort_t* bufB = (ushort_t*)(ws + off); off += (size_t)B * PROWS * ROWP * sizeof(ushort_t);
    ushort_t* wpre = (ushort_t*)(ws + off); off += (size_t)2 * 36864 * sizeof(ushort_t);
    ushort_t* w0t  = (ushort_t*)(ws + off); off += (size_t)2 * 110592 * sizeof(ushort_t);
    ushort_t* w1t  = (ushort_t*)(ws + off); off += (size_t)2 * 110592 * sizeof(ushort_t);
    // specT aliases bufB: consumed by pregemm before conv0 first writes bufB
    ushort_t* specT = bufB;

    // all weight fragments in one dispatch
    wfrag_all_kernel<<<(36864 + 2 * 110592 + 255) / 256, 256, 0, stream>>>(
        pre_w, conv0_w, conv1_w, wpre, w0t, w1t);

    // segment mean (with inline duration scan) + transpose to time-major split bf16
    segmean_kernel<<<B * C_IN, 256, 0, stream>>>(x, w, spec);
    dim3 gt(N_PH / 32, (C_IN / 32) * B);
    transpose_spec_kernel<<<gt, 256, 0, stream>>>(spec, specT);

    dim3 gg(N_PH / 64, B);
    // pre linear: specT (pitch N_PH rows) -> bufA (mask applied for conv0 input)
    gemm_fused_kernel<<<gg, 256, 0, stream>>>(specT, N_PH, wpre, pre_b, x_mask,
                                              ln0_g, ln0_b, bufA,
                                              nullptr, nullptr, nullptr, 1, 0, 1, 0);
    // block 0: bufA -> bufB  (out = ln0*mask, + conv1's leading mask)
    gemm_fused_kernel<<<gg, 256, 0, stream>>>(bufA + ROWP, PROWS, w0t, conv0_b, x_mask,
                                              ln0_g, ln0_b, bufB,
                                              nullptr, nullptr, nullptr, 3, 1, 2, 0);
    // block 1 + fused final projection: bufB -> out
    gemm_fused_kernel<<<gg, 256, 0, stream>>>(bufB + ROWP, PROWS, w1t, conv1_b, x_mask,
                                              ln1_g, ln1_b, bufA,
                                              lin_w, lin_b, out, 3, 1, 1, 1);
}